// Round 2
// baseline (205.328 us; speedup 1.0000x reference)
//
#include <hip/hip_runtime.h>
#include <cstddef>

#define NN 1024
#define CL 384
#define CP 128
#define NH 8
#define KS 32
#define HK 256

// ---------------- Kernel 1: LayerNorm + value projection ----------------
__global__ __launch_bounds__(256) void k_ln_value(
    const float* __restrict__ local_, const float* __restrict__ ln_scale,
    const float* __restrict__ ln_offset, const float* __restrict__ Wv,
    float* __restrict__ value)
{
    __shared__ float ln_s[4][CL];
    const int tid = threadIdx.x;
    const int w = tid >> 6, lane = tid & 63;
    const int r = blockIdx.x * 4 + w;
    const float* lp = local_ + (size_t)r * CL;
    float x[6]; float s1 = 0.f, s2 = 0.f;
#pragma unroll
    for (int k = 0; k < 6; ++k) { x[k] = lp[lane + 64*k]; s1 += x[k]; s2 += x[k]*x[k]; }
#pragma unroll
    for (int m = 1; m < 64; m <<= 1) { s1 += __shfl_xor(s1, m); s2 += __shfl_xor(s2, m); }
    const float mean = s1 * (1.f/CL);
    const float var  = fmaxf(s2 * (1.f/CL) - mean*mean, 0.f);
    const float rstd = rsqrtf(var + 1e-5f);
#pragma unroll
    for (int k = 0; k < 6; ++k) {
        const int c = lane + 64*k;
        ln_s[w][c] = (x[k]-mean)*rstd*ln_scale[c] + ln_offset[c];
    }
    __syncthreads();
    const int m_ = tid;   // output column 0..255
    float acc0=0.f, acc1=0.f, acc2=0.f, acc3=0.f;
    for (int c0 = 0; c0 < CL; c0 += 8) {
        float wv[8];
#pragma unroll
        for (int cc = 0; cc < 8; ++cc) wv[cc] = Wv[(size_t)(c0+cc)*HK + m_];
        {
            const float4 a = *(const float4*)&ln_s[0][c0];
            const float4 b = *(const float4*)&ln_s[0][c0+4];
            acc0 += a.x*wv[0]+a.y*wv[1]+a.z*wv[2]+a.w*wv[3]+b.x*wv[4]+b.y*wv[5]+b.z*wv[6]+b.w*wv[7];
        }
        {
            const float4 a = *(const float4*)&ln_s[1][c0];
            const float4 b = *(const float4*)&ln_s[1][c0+4];
            acc1 += a.x*wv[0]+a.y*wv[1]+a.z*wv[2]+a.w*wv[3]+b.x*wv[4]+b.y*wv[5]+b.z*wv[6]+b.w*wv[7];
        }
        {
            const float4 a = *(const float4*)&ln_s[2][c0];
            const float4 b = *(const float4*)&ln_s[2][c0+4];
            acc2 += a.x*wv[0]+a.y*wv[1]+a.z*wv[2]+a.w*wv[3]+b.x*wv[4]+b.y*wv[5]+b.z*wv[6]+b.w*wv[7];
        }
        {
            const float4 a = *(const float4*)&ln_s[3][c0];
            const float4 b = *(const float4*)&ln_s[3][c0+4];
            acc3 += a.x*wv[0]+a.y*wv[1]+a.z*wv[2]+a.w*wv[3]+b.x*wv[4]+b.y*wv[5]+b.z*wv[6]+b.w*wv[7];
        }
    }
    const int rb = blockIdx.x*4;
    value[(size_t)(rb+0)*HK + m_] = acc0;
    value[(size_t)(rb+1)*HK + m_] = acc1;
    value[(size_t)(rb+2)*HK + m_] = acc2;
    value[(size_t)(rb+3)*HK + m_] = acc3;
}

// ---------------- Kernel 2: pair-bias attention, 2 rows per block ----------------
// logits LDS layout: lg[ti*8192 + h*1024 + (j ^ (h<<2))]  (xor swizzle vs banks)
__global__ __launch_bounds__(512, 4) void k_attn(
    const float* __restrict__ pair, const int* __restrict__ mask,
    const float* __restrict__ Wa, const float* __restrict__ value,
    const float* __restrict__ Wo, float* __restrict__ outp)
{
    __shared__ float lg[2*NH*NN];   // 65536 B

    const int tid = threadIdx.x;
    const int wv_ = tid >> 6;       // wave 0..7
    const int lane = tid & 63;
    const int sub5 = lane & 31;     // 32 lanes share one j
    const int jq2 = lane >> 5;      // 2 j per wave-iter
    const int i0 = blockIdx.x * 2;

    const bool bm0 = mask[i0]   != 0;
    const bool bm1 = mask[i0+1] != 0;

    // W_attn rows sub5*4 .. sub5*4+3, all 8 heads -> 32 regs
    float wreg[32];
    {
        const float4* wp = (const float4*)(Wa + sub5*32);
#pragma unroll
        for (int k = 0; k < 8; ++k) {
            const float4 t4 = wp[k];
            wreg[4*k+0]=t4.x; wreg[4*k+1]=t4.y; wreg[4*k+2]=t4.z; wreg[4*k+3]=t4.w;
        }
    }

    const float* pb0 = pair + (size_t)i0*NN*CP + sub5*4;
    const float* pb1 = pb0 + (size_t)NN*CP;

    // ---- Phase A: stream pair, compute masked logits into LDS ----
    for (int t = 0; t < 64; ++t) {
        const int j = t*16 + wv_*2 + jq2;
        const float4 a = *(const float4*)(pb0 + (size_t)j*CP);
        const float4 b = *(const float4*)(pb1 + (size_t)j*CP);
        const int mj = mask[j];
        const float av[4] = {a.x,a.y,a.z,a.w};
        const float bv[4] = {b.x,b.y,b.z,b.w};
        float acc[16];
#pragma unroll
        for (int k = 0; k < 16; ++k) acc[k] = 0.f;
#pragma unroll
        for (int cc = 0; cc < 4; ++cc) {
#pragma unroll
            for (int h = 0; h < NH; ++h) {
                const float wgt = wreg[cc*8+h];
                acc[h]   += av[cc]*wgt;   // ti = 0
                acc[8+h] += bv[cc]*wgt;   // ti = 1
            }
        }
        // recursive-halving reduce-scatter over the 32-lane group
        const bool q16 = (sub5 & 16) != 0;
        float r8[8];
#pragma unroll
        for (int k = 0; k < 8; ++k) {
            const float keep = q16 ? acc[k+8] : acc[k];
            const float send = q16 ? acc[k] : acc[k+8];
            r8[k] = keep + __shfl_xor(send, 16);
        }
        const bool q8 = (sub5 & 8) != 0;
        float r4[4];
#pragma unroll
        for (int k = 0; k < 4; ++k) {
            const float keep = q8 ? r8[k+4] : r8[k];
            const float send = q8 ? r8[k] : r8[k+4];
            r4[k] = keep + __shfl_xor(send, 8);
        }
        const bool q4 = (sub5 & 4) != 0;
        float r2[2];
#pragma unroll
        for (int k = 0; k < 2; ++k) {
            const float keep = q4 ? r4[k+2] : r4[k];
            const float send = q4 ? r4[k] : r4[k+2];
            r2[k] = keep + __shfl_xor(send, 4);
        }
        const bool q2 = (sub5 & 2) != 0;
        const float keep1 = q2 ? r2[1] : r2[0];
        const float send1 = q2 ? r2[0] : r2[1];
        const float r1 = keep1 + __shfl_xor(send1, 2);
        const float fin = r1 + __shfl_xor(r1, 1);
        if ((sub5 & 1) == 0) {
            const int vidx = sub5 >> 1;          // ti*8 + h
            const int ti = vidx >> 3;
            const int h  = vidx & 7;
            const bool mi = ti ? bm1 : bm0;
            const float val = (mi && (mj != 0)) ? fin : -1e9f;
            lg[ti*(NH*NN) + h*NN + (j ^ (h<<2))] = val;
        }
    }
    __syncthreads();

    // ---- Phase B: exact softmax per (ti,h); 16 groups x 32 threads ----
    {
        const int g = tid >> 5, l32 = tid & 31;
        const int sti = g >> 3, sh = g & 7;
        const int shx = sh << 2;
        float* base = lg + sti*(NH*NN) + sh*NN;
        const bool mi = sti ? bm1 : bm0;
        float mx = -3.0e38f;
#pragma unroll 4
        for (int k = 0; k < 32; ++k) mx = fmaxf(mx, base[(l32 + 32*k) ^ shx]);
#pragma unroll
        for (int m = 1; m < 32; m <<= 1) mx = fmaxf(mx, __shfl_xor(mx, m));
        float se = 0.f;
#pragma unroll 4
        for (int k = 0; k < 32; ++k) se += __expf(base[(l32 + 32*k) ^ shx] - mx);
#pragma unroll
        for (int m = 1; m < 32; m <<= 1) se += __shfl_xor(se, m);
        const float inv = 1.f / se;
#pragma unroll 4
        for (int k = 0; k < 32; ++k) {
            const int j = l32 + 32*k;
            const int ad = j ^ shx;
            float p = __expf(base[ad] - mx) * inv;
            if (!(mi && (mask[j] != 0))) p = 0.f;
            base[ad] = p;
        }
    }
    __syncthreads();

    // ---- Phase C: out[ti,h,c] = sum_j p * value; thread=(j-half, h, c), both ti ----
    float ac0 = 0.f, ac1 = 0.f;
    {
        const int half = tid >> 8;
        const int ph = (tid >> 5) & 7;
        const int pc = tid & 31;
        const int chx = ph << 2;
        const float* vp = value + ph*KS + pc;
        const float* pp0 = lg + ph*NN;
        const float* pp1 = lg + NH*NN + ph*NN;
        const int jb = half*512;
        for (int j0 = jb; j0 < jb+512; j0 += 8) {
            // swizzle-correct addresses: elements j0..j0+3 live at (j0)^chx,
            // elements j0+4..j0+7 live at (j0+4)^chx (NOT sjA+4 when chx bit2 set!)
            const int sjA = j0 ^ chx;
            const int sjB = (j0 + 4) ^ chx;
            const float4 q0a = *(const float4*)&pp0[sjA];
            const float4 q0b = *(const float4*)&pp0[sjB];
            const float4 q1a = *(const float4*)&pp1[sjA];
            const float4 q1b = *(const float4*)&pp1[sjB];
            const float v0 = vp[(size_t)(j0+0)*HK];
            const float v1 = vp[(size_t)(j0+1)*HK];
            const float v2 = vp[(size_t)(j0+2)*HK];
            const float v3 = vp[(size_t)(j0+3)*HK];
            const float v4 = vp[(size_t)(j0+4)*HK];
            const float v5 = vp[(size_t)(j0+5)*HK];
            const float v6 = vp[(size_t)(j0+6)*HK];
            const float v7 = vp[(size_t)(j0+7)*HK];
            ac0 += q0a.x*v0 + q0a.y*v1 + q0a.z*v2 + q0a.w*v3
                 + q0b.x*v4 + q0b.y*v5 + q0b.z*v6 + q0b.w*v7;
            ac1 += q1a.x*v0 + q1a.y*v1 + q1a.z*v2 + q1a.w*v3
                 + q1b.x*v4 + q1b.y*v5 + q1b.z*v6 + q1b.w*v7;
        }
    }
    __syncthreads();                 // all p reads done before overwriting lg
    lg[2*tid]   = ac0;               // partials, region [0, 1024)
    lg[2*tid+1] = ac1;
    __syncthreads();
    {   // combine the two j-halves -> out vector at lg[4096 + cti*HK + m]
        const int cti = tid >> 8;
        const int hc = tid & 255;
        const float s = lg[2*hc + cti] + lg[2*(256 + hc) + cti];
        lg[4096 + cti*HK + hc] = s;
    }
    __syncthreads();

    // ---- Phase D: final projection out @ W_out ----
    if (tid < CL) {
        const int o = tid;
        float a0 = 0.f, a1 = 0.f;
        for (int m = 0; m < HK; m += 4) {
            const float4 x0 = *(const float4*)&lg[4096 + m];
            const float4 x1 = *(const float4*)&lg[4096 + HK + m];
            const float w0 = Wo[(size_t)(m+0)*CL + o];
            const float w1 = Wo[(size_t)(m+1)*CL + o];
            const float w2 = Wo[(size_t)(m+2)*CL + o];
            const float w3 = Wo[(size_t)(m+3)*CL + o];
            a0 += x0.x*w0 + x0.y*w1 + x0.z*w2 + x0.w*w3;
            a1 += x1.x*w0 + x1.y*w1 + x1.z*w2 + x1.w*w3;
        }
        outp[(size_t)(i0+0)*CL + o] = a0;
        outp[(size_t)(i0+1)*CL + o] = a1;
    }
}

extern "C" void kernel_launch(void* const* d_in, const int* in_sizes, int n_in,
                              void* d_out, int out_size, void* d_ws, size_t ws_size,
                              hipStream_t stream)
{
    (void)in_sizes; (void)n_in; (void)out_size; (void)ws_size;
    const float* local_ = (const float*)d_in[0];
    const float* pair   = (const float*)d_in[1];
    const int*   mask   = (const int*)d_in[2];
    const float* scale  = (const float*)d_in[3];
    const float* offset = (const float*)d_in[4];
    const float* Wv     = (const float*)d_in[5];
    const float* Wa     = (const float*)d_in[6];
    const float* Wo     = (const float*)d_in[7];
    float* value = (float*)d_ws;          // 1 MiB scratch
    k_ln_value<<<NN/4, 256, 0, stream>>>(local_, scale, offset, Wv, value);
    k_attn<<<NN/2, 512, 0, stream>>>(pair, mask, Wa, value, Wo, (float*)d_out);
}